// Round 6
// baseline (293.102 us; speedup 1.0000x reference)
//
#include <hip/hip_runtime.h>
#include <math.h>
#include <stdint.h>

#define B 4
#define S 4096
#define E 768
#define H 64
#define NMAT 192   // 3*64 output columns (q|k|v)

typedef _Float16 half_t;
typedef __attribute__((ext_vector_type(8))) _Float16 half8;
typedef __attribute__((ext_vector_type(4))) _Float16 half4;
typedef __attribute__((ext_vector_type(4))) float f32x4;
typedef __attribute__((ext_vector_type(16))) float f32x16;

#define LOG2E 1.4426950408889634f

// ---------------- W prep: fp16 Dekker split ----------------
// Wst layout: [kstep 24][n 192][part 2][32]  (n = mat*64+h, part 0=hi 1=lo)
__global__ __launch_bounds__(256) void wprep_kernel(
    const float* __restrict__ Wq, const float* __restrict__ Wk,
    const float* __restrict__ Wv, half_t* __restrict__ Wst)
{
    int gid = blockIdx.x * 256 + threadIdx.x;     // 0..147455
    int m = gid / (H * E);
    int rem = gid - m * (H * E);
    int h = rem / E;
    int e = rem - h * E;
    const float* W = (m == 0) ? Wq : (m == 1) ? Wk : Wv;
    float val = W[h * E + e];
    half_t hi = (half_t)val;
    float lo = val - (float)hi;
    int n = m * H + h;
    int ks = e >> 5, kk = e & 31;
    size_t base = ((size_t)(ks * NMAT + n) * 2) * 32 + kk;
    Wst[base]      = hi;
    Wst[base + 32] = (half_t)lo;
}

// ---------------- Projection: barrier-free, LDS-free MFMA GEMM ----------------
// grid 256 x 256 thr (4 independent waves of 16 M-rows). Each wave computes
// ALL 12 N-ctiles (q 0..3, k 4..7, v 8..11), reading pre-split Wst directly
// from global in B-frag layout (L2-resident, 576 KB). x split in-reg.
// Accumulation order per ctile identical to round 4 -> q/k/v bit-identical.
__global__ __launch_bounds__(256) void proj_kernel(
    const float* __restrict__ x, const half_t* __restrict__ Wst,
    half_t* __restrict__ qhi, half_t* __restrict__ qlo,
    half_t* __restrict__ khi, half_t* __restrict__ klo,
    half_t* __restrict__ vt)
{
    const int t = threadIdx.x;
    const int w = t >> 6, lane = t & 63;
    const int col = lane & 15, quad = lane >> 4;
    const int mrow = blockIdx.x * 64 + w * 16 + col;

    f32x4 acc[12];
    #pragma unroll
    for (int i = 0; i < 12; ++i) acc[i] = (f32x4){0.f, 0.f, 0.f, 0.f};

    for (int ks = 0; ks < 24; ++ks) {
        // A fragment: x fp32 -> f16 hi/lo (identical to r4)
        const float* xp = x + (size_t)mrow * E + ks * 32 + quad * 8;
        float4 xa = *(const float4*)xp;
        float4 xb = *(const float4*)(xp + 4);
        float xv[8] = {xa.x, xa.y, xa.z, xa.w, xb.x, xb.y, xb.z, xb.w};
        half8 ah, al;
        #pragma unroll
        for (int j = 0; j < 8; ++j) {
            half_t hi = (half_t)xv[j];
            ah[j] = hi;
            al[j] = (half_t)(xv[j] - (float)hi);
        }

        const half_t* wbase = Wst + (size_t)ks * (NMAT * 64);
        #pragma unroll
        for (int c = 0; c < 12; ++c) {
            const half_t* wr = wbase + (size_t)(c * 16 + col) * 64;
            half8 bh = *(const half8*)(wr + quad * 8);
            acc[c] = __builtin_amdgcn_mfma_f32_16x16x32_f16(ah, bh, acc[c], 0, 0, 0);
            if (c < 8) {   // q,k: 3-combo split; v: single
                half8 bl = *(const half8*)(wr + 32 + quad * 8);
                acc[c] = __builtin_amdgcn_mfma_f32_16x16x32_f16(al, bh, acc[c], 0, 0, 0);
                acc[c] = __builtin_amdgcn_mfma_f32_16x16x32_f16(ah, bl, acc[c], 0, 0, 0);
            }
        }
    }

    // Epilogue. C-layout (16x16): row = quad*4+r, col = lane&15. Same values as r4.
    const int srow0 = blockIdx.x * 64 + w * 16 + quad * 4;
    #pragma unroll
    for (int c = 0; c < 4; ++c) {
        const int hcol = c * 16 + col;
        #pragma unroll
        for (int r = 0; r < 4; ++r) {
            int srow = srow0 + r;
            float vq = acc[c][r];
            half_t hq = (half_t)vq;
            qhi[(size_t)srow * H + hcol] = hq;
            qlo[(size_t)srow * H + hcol] = (half_t)(vq - (float)hq);
            float vk = acc[c + 4][r];
            half_t hk = (half_t)vk;
            khi[(size_t)srow * H + hcol] = hk;
            klo[(size_t)srow * H + hcol] = (half_t)(vk - (float)hk);
        }
        half4 pk;
        #pragma unroll
        for (int r = 0; r < 4; ++r) pk[r] = (half_t)acc[c + 8][r];
        int bb = srow0 >> 12, s0 = srow0 & (S - 1);
        *(half4*)(vt + ((size_t)(bb * H + hcol)) * S + s0) = pk;
    }
}

// ---------------- Flash attention: async staging, 2 blocks/CU ----------------
// grid 256 x 512 thr. Block: 64 q-rows. 8 waves = 2 qsub(32 rows) x 4 ksw(32 keys).
// 128-key double-buffered stages of kh+vt via global_load_lds; the XOR swizzle is
// baked into the per-lane SOURCE address, computed PER ISSUE (r5 bug: vt swizzle
// depends on dim&15, which changes across the 4 issues). LDS dest is wave-uniform
// + lane*16. kl read directly from global. LDS 80 KB -> 2 blocks/CU.
__global__ __launch_bounds__(512, 4) void flash_kernel(
    const half_t* __restrict__ qhi, const half_t* __restrict__ qlo,
    const half_t* __restrict__ khi, const half_t* __restrict__ klo,
    const half_t* __restrict__ vt, float* __restrict__ out)
{
    __shared__ __align__(16) char smem[81920];   // buf0 32K | buf1 32K | p_s 16K

    const int t = threadIdx.x;
    const int w = t >> 6, lane = t & 63;
    const int n32 = lane & 31, l5 = lane >> 5;
    const int qsub = w & 1, ksw = w >> 1;

    const int b = blockIdx.x >> 6;
    const int qtile = blockIdx.x & 63;
    const int qrow0 = b * S + qtile * 64;
    const int wrow0 = qrow0 + qsub * 32;

    half_t* p_s = (half_t*)(smem + 65536);

    // Q fragments (32x32x16 A-layout: m=lane&31, k=l5*8+j), 4 ksteps, hi/lo
    half8 qh[4], ql[4];
    #pragma unroll
    for (int ks = 0; ks < 4; ++ks) {
        size_t off = (size_t)(wrow0 + n32) * H + ks * 16 + l5 * 8;
        qh[ks] = *(const half8*)(qhi + off);
        ql[ks] = *(const half8*)(qlo + off);
    }

    f32x16 O[2];
    #pragma unroll
    for (int i = 0; i < 2; ++i)
        #pragma unroll
        for (int r = 0; r < 16; ++r) O[i][r] = 0.f;
    float lacc[16];
    #pragma unroll
    for (int r = 0; r < 16; ++r) lacc[r] = 0.f;

    const half_t* kh_g = khi + (size_t)b * S * H;
    const half_t* kl_g = klo + (size_t)b * S * H;
    const half_t* vt_g = vt + (size_t)b * H * S;

    // --- async staging setup: waves 0-3 stage kh (swizzle c^(key&7), key&7
    //     issue-invariant -> single base); waves 4-7 stage vt (swizzle
    //     c^(dim&15), dim changes per issue -> 4 per-issue bases) ---
    const char* stage_src[4];
    int str_tile;
    uint32_t lds_off;
    if (w < 4) {
        int key = w * 32 + (lane >> 3);
        int c = (lane & 7) ^ (key & 7);
        const char* b0 = (const char*)kh_g + (size_t)key * 128 + c * 16;
        #pragma unroll
        for (int i = 0; i < 4; ++i) stage_src[i] = b0 + i * (8 * 128);
        str_tile = 128 * 128;     // +128 keys per tile
        lds_off = (uint32_t)w * 4096;
    } else {
        #pragma unroll
        for (int i = 0; i < 4; ++i) {
            int dim = (w - 4) * 16 + i * 4 + (lane >> 4);
            int c = (lane & 15) ^ (dim & 15);
            stage_src[i] = (const char*)vt_g + (size_t)dim * (S * 2) + c * 16;
        }
        str_tile = 128 * 2;       // +128 keys per tile
        lds_off = 16384 + (uint32_t)(w - 4) * 4096;
    }

    auto stage = [&](int kt, int buf) {
        char* dstb = smem + buf * 32768 + lds_off;
        #pragma unroll
        for (int i = 0; i < 4; ++i) {
            __builtin_amdgcn_global_load_lds(
                (const __attribute__((address_space(1))) unsigned int*)(stage_src[i] + (size_t)kt * str_tile),
                (__attribute__((address_space(3))) unsigned int*)(dstb + i * 1024),
                16, 0, 0);
        }
    };

    stage(0, 0);

    const int keyl = ksw * 32 + n32;          // this lane's key within stage
    const int pc = keyl >> 3, po = keyl & 7;
    const int prow = qsub * 32 + n32;
    const half_t* klp = kl_g + (size_t)keyl * 64;   // direct K-lo row

    for (int kt = 0; kt < 32; ++kt) {
        const int cur = kt & 1;
        __syncthreads();                       // vmcnt drained -> buf cur ready
        if (kt < 31) stage(kt + 1, cur ^ 1);

        const half_t* khs = (const half_t*)(smem + cur * 32768);
        const half_t* vts = (const half_t*)(smem + cur * 32768 + 16384);
        const half_t* klrow = klp + (size_t)kt * (128 * 64);

        half8 bl4[4];
        #pragma unroll
        for (int ks = 0; ks < 4; ++ks)
            bl4[ks] = *(const half8*)(klrow + ks * 16 + l5 * 8);

        // ---- QK^T: 32x32 scores, fp16 3-combo split (order as r4) ----
        f32x16 acc;
        #pragma unroll
        for (int r = 0; r < 16; ++r) acc[r] = 0.f;
        #pragma unroll
        for (int ks = 0; ks < 4; ++ks) {
            int phys = ((ks * 2 + l5) ^ (keyl & 7)) * 8;
            half8 bh = *(const half8*)(khs + keyl * 64 + phys);
            acc = __builtin_amdgcn_mfma_f32_32x32x16_f16(qh[ks], bh, acc, 0, 0, 0);
            acc = __builtin_amdgcn_mfma_f32_32x32x16_f16(ql[ks], bh, acc, 0, 0, 0);
            acc = __builtin_amdgcn_mfma_f32_32x32x16_f16(qh[ks], bl4[ks], acc, 0, 0, 0);
        }

        // ---- fixed-max integer softmax; p -> LDS (swizzled row-major) ----
        #pragma unroll
        for (int r = 0; r < 16; ++r) {
            float sc = floorf(acc[r] * 0.125f);
            float p = exp2f((sc - 8.0f) * LOG2E);  // scores bounded << 8
            lacc[r] += p;
            int rowl = qsub * 32 + (r & 3) + 8 * (r >> 2) + 4 * l5;
            p_s[rowl * 128 + ((pc ^ (rowl & 15)) << 3) + po] = (half_t)p;
        }

        // ---- PV: O += P * V^T (same-wave p_s round trip) ----
        #pragma unroll
        for (int ks2 = 0; ks2 < 2; ++ks2) {
            int c = ksw * 4 + ks2 * 2 + l5;
            half8 pf = *(const half8*)(p_s + prow * 128 + ((c ^ (prow & 15)) << 3));
            #pragma unroll
            for (int nct = 0; nct < 2; ++nct) {
                int dim = nct * 32 + n32;
                half8 vf = *(const half8*)(vts + dim * 128 + ((c ^ (dim & 15)) << 3));
                O[nct] = __builtin_amdgcn_mfma_f32_32x32x16_f16(pf, vf, O[nct], 0, 0, 0);
            }
        }
    }

    // ---- reduce l across the 32 key-lanes ----
    #pragma unroll
    for (int mask = 1; mask <= 16; mask <<= 1) {
        #pragma unroll
        for (int r = 0; r < 16; ++r) lacc[r] += __shfl_xor(lacc[r], mask);
    }

    // ---- combine the 4 key-split partials via LDS ----
    __syncthreads();
    float* Oc  = (float*)smem;                  // [4 ksw][64 rows][64 dims] = 64K
    float* l_s = (float*)(smem + 65536);        // in dead p_s region
    #pragma unroll
    for (int nct = 0; nct < 2; ++nct) {
        #pragma unroll
        for (int r = 0; r < 16; ++r) {
            int rowl = qsub * 32 + (r & 3) + 8 * (r >> 2) + 4 * l5;
            Oc[(ksw * 64 + rowl) * 64 + nct * 32 + n32] = O[nct][r];
        }
    }
    if (n32 == 0) {
        #pragma unroll
        for (int r = 0; r < 16; ++r) {
            int rowl = qsub * 32 + (r & 3) + 8 * (r >> 2) + 4 * l5;
            l_s[ksw * 64 + rowl] = lacc[r];
        }
    }
    __syncthreads();

    {
        int row = t >> 3;            // 0..63
        int d0 = (t & 7) * 8;        // 0..56
        float den = 0.f;
        float4 na = make_float4(0.f, 0.f, 0.f, 0.f);
        float4 nb = make_float4(0.f, 0.f, 0.f, 0.f);
        #pragma unroll
        for (int k = 0; k < 4; ++k) {
            den += l_s[k * 64 + row];
            const float* oc = Oc + (size_t)(k * 64 + row) * 64 + d0;
            float4 a = *(const float4*)oc;
            float4 bq = *(const float4*)(oc + 4);
            na.x += a.x;  na.y += a.y;  na.z += a.z;  na.w += a.w;
            nb.x += bq.x; nb.y += bq.y; nb.z += bq.z; nb.w += bq.w;
        }
        float inv = 1.f / den;
        float4 o1 = make_float4(na.x * inv, na.y * inv, na.z * inv, na.w * inv);
        float4 o2 = make_float4(nb.x * inv, nb.y * inv, nb.z * inv, nb.w * inv);
        float* op = out + (size_t)(qrow0 + row) * H + d0;
        *(float4*)op = o1;
        *(float4*)(op + 4) = o2;
    }
}

extern "C" void kernel_launch(void* const* d_in, const int* in_sizes, int n_in,
                              void* d_out, int out_size, void* d_ws, size_t ws_size,
                              hipStream_t stream) {
    const float* x  = (const float*)d_in[0];
    const float* Wq = (const float*)d_in[1];
    const float* Wk = (const float*)d_in[2];
    const float* Wv = (const float*)d_in[3];
    float* outp = (float*)d_out;

    const size_t N = (size_t)B * S * H;          // 1,048,576
    half_t* qhi = (half_t*)d_ws;
    half_t* qlo = qhi + N;
    half_t* khi = qlo + N;
    half_t* klo = khi + N;
    half_t* vt  = klo + N;
    half_t* Wst = vt + N;                        // 294912 halves

    wprep_kernel<<<(3 * H * E) / 256, 256, 0, stream>>>(Wq, Wk, Wv, Wst);
    proj_kernel<<<(B * S) / 64, 256, 0, stream>>>(x, Wst, qhi, qlo, khi, klo, vt);
    flash_kernel<<<B * (S / 64), 512, 0, stream>>>(qhi, qlo, khi, klo, vt, outp);
}

// Round 8
// 224.476 us; speedup vs baseline: 1.3057x; 1.3057x over previous
//
#include <hip/hip_runtime.h>
#include <math.h>
#include <stdint.h>

#define B 4
#define S 4096
#define E 768
#define H 64
#define NMAT 192   // 3*64 output columns (q|k|v)

typedef _Float16 half_t;
typedef __attribute__((ext_vector_type(8))) _Float16 half8;
typedef __attribute__((ext_vector_type(4))) _Float16 half4;
typedef __attribute__((ext_vector_type(4))) float f32x4;
typedef __attribute__((ext_vector_type(16))) float f32x16;

#define LOG2E 1.4426950408889634f
#define AS1 __attribute__((address_space(1)))
#define AS3 __attribute__((address_space(3)))

// ---------------- W prep: fp16 Dekker split ----------------
// Wst layout: [kstep 24][n 192][part 2][32]  (n = mat*64+h, part 0=hi 1=lo)
__global__ __launch_bounds__(256) void wprep_kernel(
    const float* __restrict__ Wq, const float* __restrict__ Wk,
    const float* __restrict__ Wv, half_t* __restrict__ Wst)
{
    int gid = blockIdx.x * 256 + threadIdx.x;     // 0..147455
    int m = gid / (H * E);
    int rem = gid - m * (H * E);
    int h = rem / E;
    int e = rem - h * E;
    const float* W = (m == 0) ? Wq : (m == 1) ? Wk : Wv;
    float val = W[h * E + e];
    half_t hi = (half_t)val;
    float lo = val - (float)hi;
    int n = m * H + h;
    int ks = e >> 5, kk = e & 31;
    size_t base = ((size_t)(ks * NMAT + n) * 2) * 32 + kk;
    Wst[base]      = hi;
    Wst[base + 32] = (half_t)lo;
}

// ---------------- Projection: LDS-free, barrier-free, 4 waves/SIMD ----------------
// grid 1024 x 256 thr. Block: 16 M-rows; wave w = nsplit handles 3 ctiles
// (q ctile w, k ctile 4+w, v ctile 8+w). 4 blocks/CU -> 16 waves/CU.
// Per-ctile MFMA sequence identical to r4/r6 -> outputs bit-identical.
__global__ __launch_bounds__(256) void proj_kernel(
    const float* __restrict__ x, const half_t* __restrict__ Wst,
    half_t* __restrict__ qhi, half_t* __restrict__ qlo,
    half_t* __restrict__ khi, half_t* __restrict__ klo,
    half_t* __restrict__ vt)
{
    const int t = threadIdx.x;
    const int w = t >> 6, lane = t & 63;          // w = nsplit 0..3
    const int col = lane & 15, quad = lane >> 4;
    const int mrow = blockIdx.x * 16 + col;

    f32x4 acc[3];
    #pragma unroll
    for (int i = 0; i < 3; ++i) acc[i] = (f32x4){0.f, 0.f, 0.f, 0.f};

    for (int ks = 0; ks < 24; ++ks) {
        const float* xp = x + (size_t)mrow * E + ks * 32 + quad * 8;
        float4 xa = *(const float4*)xp;
        float4 xb = *(const float4*)(xp + 4);
        float xv[8] = {xa.x, xa.y, xa.z, xa.w, xb.x, xb.y, xb.z, xb.w};
        half8 ah, al;
        #pragma unroll
        for (int j = 0; j < 8; ++j) {
            half_t hi = (half_t)xv[j];
            ah[j] = hi;
            al[j] = (half_t)(xv[j] - (float)hi);
        }

        const half_t* wbase = Wst + (size_t)ks * (NMAT * 64);
        #pragma unroll
        for (int g = 0; g < 3; ++g) {             // g=0:q g=1:k g=2:v
            int c = g * 4 + w;
            const half_t* wr = wbase + (size_t)(c * 16 + col) * 64;
            half8 bh = *(const half8*)(wr + quad * 8);
            acc[g] = __builtin_amdgcn_mfma_f32_16x16x32_f16(ah, bh, acc[g], 0, 0, 0);
            if (g < 2) {
                half8 bl = *(const half8*)(wr + 32 + quad * 8);
                acc[g] = __builtin_amdgcn_mfma_f32_16x16x32_f16(al, bh, acc[g], 0, 0, 0);
                acc[g] = __builtin_amdgcn_mfma_f32_16x16x32_f16(ah, bl, acc[g], 0, 0, 0);
            }
        }
    }

    // Epilogue. C-layout (16x16): row = quad*4+r, col = lane&15. Values as r6.
    const int srow0 = blockIdx.x * 16 + quad * 4;
    const int hcol = w * 16 + col;
    #pragma unroll
    for (int r = 0; r < 4; ++r) {
        int srow = srow0 + r;
        float vq = acc[0][r];
        half_t hq = (half_t)vq;
        qhi[(size_t)srow * H + hcol] = hq;
        qlo[(size_t)srow * H + hcol] = (half_t)(vq - (float)hq);
        float vk = acc[1][r];
        half_t hk = (half_t)vk;
        khi[(size_t)srow * H + hcol] = hk;
        klo[(size_t)srow * H + hcol] = (half_t)(vk - (float)hk);
    }
    {   // v transposed [b][dim][S]
        half4 pk;
        #pragma unroll
        for (int r = 0; r < 4; ++r) pk[r] = (half_t)acc[2][r];
        int bb = srow0 >> 12, s0 = srow0 & (S - 1);
        *(half4*)(vt + ((size_t)(bb * H + hcol)) * S + s0) = pk;
    }
}

// ---------------- Flash attention: async staging + kl register prefetch ----------------
// grid 512 x 256 thr. Block: 32 q-rows; 4 waves = ksw (32 keys each of KT=128).
// kh+vt double-buffered via global_load_lds with PER-ISSUE precomputed source
// pointers (r6-proven pattern; swizzle baked into each issue's own address —
// r5/r7 bugs both came from deriving these by striding). kl prefetched into
// registers one tile ahead, issued AFTER its last use, so the only vmcnt drain
// is the top-of-loop __syncthreads. LDS 72 KB -> 2 blocks/CU.
__global__ __launch_bounds__(256, 2) void flash_kernel(
    const half_t* __restrict__ qhi, const half_t* __restrict__ qlo,
    const half_t* __restrict__ khi, const half_t* __restrict__ klo,
    const half_t* __restrict__ vt, float* __restrict__ out)
{
    __shared__ __align__(16) char smem[73728];   // buf0 32K | buf1 32K | p_s 8K

    const int t = threadIdx.x;
    const int w = t >> 6, lane = t & 63;         // w = ksw 0..3
    const int n32 = lane & 31, l5 = lane >> 5;

    const int b = blockIdx.x >> 7;
    const int qtile = blockIdx.x & 127;
    const int qrow0 = b * S + qtile * 32;

    half_t* p_s = (half_t*)(smem + 65536);

    // Q fragments (32x32x16 A-layout: m=lane&31, k=l5*8+j), 4 ksteps, hi/lo
    half8 qh[4], ql[4];
    #pragma unroll
    for (int ks = 0; ks < 4; ++ks) {
        size_t off = (size_t)(qrow0 + n32) * H + ks * 16 + l5 * 8;
        qh[ks] = *(const half8*)(qhi + off);
        ql[ks] = *(const half8*)(qlo + off);
    }

    f32x16 O[2];
    #pragma unroll
    for (int i = 0; i < 2; ++i)
        #pragma unroll
        for (int r = 0; r < 16; ++r) O[i][r] = 0.f;
    float lacc[16];
    #pragma unroll
    for (int r = 0; r < 16; ++r) lacc[r] = 0.f;

    const half_t* kh_g = khi + (size_t)b * S * H;
    const half_t* kl_g = klo + (size_t)b * S * H;
    const half_t* vt_g = vt + (size_t)b * H * S;

    // --- async staging: 8 issues/wave, one precomputed source pointer each.
    // kh (waves 0-1): issue i -> key = i*16 + w*8 + (lane>>3), chunk lane&7
    //   holds logical c = (lane&7)^(key&7). LDS dest = key*128 + (lane&7)*16.
    // vt (waves 2-3): issue i -> dim = (w-2)*4 + i*8 + (lane>>4), chunk lane&15
    //   holds logical c = (lane&15)^(dim&15). LDS dest = 16384 + dim*256 + ...
    const char* stage_src[8];
    int str_tile;
    uint32_t lds_off;
    if (w < 2) {
        #pragma unroll
        for (int i = 0; i < 8; ++i) {
            int key = i * 16 + w * 8 + (lane >> 3);
            int c = (lane & 7) ^ (key & 7);
            stage_src[i] = (const char*)kh_g + (size_t)key * 128 + (size_t)c * 16;
        }
        str_tile = 128 * 128;     // +128 keys per tile (bytes)
        lds_off = (uint32_t)w * 1024;
    } else {
        #pragma unroll
        for (int i = 0; i < 8; ++i) {
            int dim = (w - 2) * 4 + i * 8 + (lane >> 4);
            int c = (lane & 15) ^ (dim & 15);
            stage_src[i] = (const char*)vt_g + (size_t)dim * (S * 2) + (size_t)c * 16;
        }
        str_tile = 128 * 2;       // +128 keys per tile (bytes)
        lds_off = 16384 + (uint32_t)(w - 2) * 1024;
    }

    auto stage = [&](int kt, int buf) {
        char* dstb = smem + buf * 32768 + lds_off;
        #pragma unroll
        for (int i = 0; i < 8; ++i)
            __builtin_amdgcn_global_load_lds(
                (const AS1 unsigned int*)(stage_src[i] + (size_t)kt * str_tile),
                (AS3 unsigned int*)(dstb + i * 2048), 16, 0, 0);
    };

    const int keyl = w * 32 + n32;            // this lane's key within stage
    const int pc = keyl >> 3, po = keyl & 7;
    const int prow = n32;                     // PV A-frag row
    const half_t* klp = kl_g + (size_t)keyl * 64;

    // prologue: stage tile 0, prefetch kl tile 0 into registers
    stage(0, 0);
    half8 bl[4];
    #pragma unroll
    for (int ks = 0; ks < 4; ++ks)
        bl[ks] = *(const half8*)(klp + ks * 16 + l5 * 8);

    for (int kt = 0; kt < 32; ++kt) {
        const int cur = kt & 1;
        __syncthreads();                      // drains stage(kt) + bl(kt) loads
        if (kt < 31) stage(kt + 1, cur ^ 1);

        const half_t* khs = (const half_t*)(smem + cur * 32768);
        const half_t* vts = (const half_t*)(smem + cur * 32768 + 16384);

        // ---- QK^T: 32x32 scores, fp16 3-combo split (order as r4/r6) ----
        f32x16 acc;
        #pragma unroll
        for (int r = 0; r < 16; ++r) acc[r] = 0.f;
        #pragma unroll
        for (int ks = 0; ks < 4; ++ks) {
            int phys = ((ks * 2 + l5) ^ (keyl & 7)) * 8;
            half8 bh = *(const half8*)(khs + keyl * 64 + phys);
            acc = __builtin_amdgcn_mfma_f32_32x32x16_f16(qh[ks], bh, acc, 0, 0, 0);
            acc = __builtin_amdgcn_mfma_f32_32x32x16_f16(ql[ks], bh, acc, 0, 0, 0);
            acc = __builtin_amdgcn_mfma_f32_32x32x16_f16(qh[ks], bl[ks], acc, 0, 0, 0);
        }

        // prefetch next tile's kl AFTER last use (in flight until next barrier)
        if (kt < 31) {
            const half_t* kln = klp + (size_t)(kt + 1) * (128 * 64);
            #pragma unroll
            for (int ks = 0; ks < 4; ++ks)
                bl[ks] = *(const half8*)(kln + ks * 16 + l5 * 8);
        }

        // ---- fixed-max integer softmax; p -> LDS (swizzled row-major) ----
        #pragma unroll
        for (int r = 0; r < 16; ++r) {
            float sc = floorf(acc[r] * 0.125f);
            float p = exp2f((sc - 8.0f) * LOG2E);  // scores bounded << 8
            lacc[r] += p;
            int rowl = (r & 3) + 8 * (r >> 2) + 4 * l5;
            p_s[rowl * 128 + ((pc ^ (rowl & 15)) << 3) + po] = (half_t)p;
        }

        // ---- PV: O += P * V^T over this wave's 32 keys ----
        #pragma unroll
        for (int ks2 = 0; ks2 < 2; ++ks2) {
            int c = w * 4 + ks2 * 2 + l5;
            half8 pf = *(const half8*)(p_s + prow * 128 + ((c ^ (prow & 15)) << 3));
            #pragma unroll
            for (int nct = 0; nct < 2; ++nct) {
                int dim = nct * 32 + n32;
                half8 vf = *(const half8*)(vts + dim * 128 + ((c ^ (dim & 15)) << 3));
                O[nct] = __builtin_amdgcn_mfma_f32_32x32x16_f16(pf, vf, O[nct], 0, 0, 0);
            }
        }
    }

    // ---- reduce l across the 32 key-lanes ----
    #pragma unroll
    for (int mask = 1; mask <= 16; mask <<= 1) {
        #pragma unroll
        for (int r = 0; r < 16; ++r) lacc[r] += __shfl_xor(lacc[r], mask);
    }

    // ---- combine the 4 key-split partials via LDS ----
    __syncthreads();
    float* Oc  = (float*)smem;                  // [4 ksw][32 rows][64 dims] = 32K
    float* l_s = (float*)(smem + 65536);        // dead p_s region
    #pragma unroll
    for (int nct = 0; nct < 2; ++nct) {
        #pragma unroll
        for (int r = 0; r < 16; ++r) {
            int rowl = (r & 3) + 8 * (r >> 2) + 4 * l5;
            Oc[(w * 32 + rowl) * 64 + nct * 32 + n32] = O[nct][r];
        }
    }
    if (n32 == 0) {
        #pragma unroll
        for (int r = 0; r < 16; ++r) {
            int rowl = (r & 3) + 8 * (r >> 2) + 4 * l5;
            l_s[w * 32 + rowl] = lacc[r];
        }
    }
    __syncthreads();

    {
        int row = t >> 3;            // 0..31
        int d0 = (t & 7) * 8;        // 0..56
        float den = 0.f;
        float4 na = make_float4(0.f, 0.f, 0.f, 0.f);
        float4 nb = make_float4(0.f, 0.f, 0.f, 0.f);
        #pragma unroll
        for (int k = 0; k < 4; ++k) {
            den += l_s[k * 32 + row];
            const float* oc = Oc + (size_t)(k * 32 + row) * 64 + d0;
            float4 a = *(const float4*)oc;
            float4 bq = *(const float4*)(oc + 4);
            na.x += a.x;  na.y += a.y;  na.z += a.z;  na.w += a.w;
            nb.x += bq.x; nb.y += bq.y; nb.z += bq.z; nb.w += bq.w;
        }
        float inv = 1.f / den;
        float4 o1 = make_float4(na.x * inv, na.y * inv, na.z * inv, na.w * inv);
        float4 o2 = make_float4(nb.x * inv, nb.y * inv, nb.z * inv, nb.w * inv);
        float* op = out + (size_t)(qrow0 + row) * H + d0;
        *(float4*)op = o1;
        *(float4*)(op + 4) = o2;
    }
}

extern "C" void kernel_launch(void* const* d_in, const int* in_sizes, int n_in,
                              void* d_out, int out_size, void* d_ws, size_t ws_size,
                              hipStream_t stream) {
    const float* x  = (const float*)d_in[0];
    const float* Wq = (const float*)d_in[1];
    const float* Wk = (const float*)d_in[2];
    const float* Wv = (const float*)d_in[3];
    float* outp = (float*)d_out;

    const size_t N = (size_t)B * S * H;          // 1,048,576
    half_t* qhi = (half_t*)d_ws;
    half_t* qlo = qhi + N;
    half_t* khi = qlo + N;
    half_t* klo = khi + N;
    half_t* vt  = klo + N;
    half_t* Wst = vt + N;                        // 294912 halves

    wprep_kernel<<<(3 * H * E) / 256, 256, 0, stream>>>(Wq, Wk, Wv, Wst);
    proj_kernel<<<(B * S) / 16, 256, 0, stream>>>(x, Wst, qhi, qlo, khi, klo, vt);
    flash_kernel<<<B * (S / 32), 256, 0, stream>>>(qhi, qlo, khi, klo, vt, outp);
}